// Round 2
// 150.685 us; speedup vs baseline: 1.0568x; 1.0568x over previous
//
#include <hip/hip_runtime.h>

// out[t,k] = x[t,:] . Mre[k,:]   (T=262144, F=100, K=2)
// Mre[k,a] = sum_ij u[ij]*A_re[k,i,j,a] - v[ij]*A_im[k,i,j,a]
//   u[ij] = pr_i*pr_j + pi_i*pi_j,  v[ij] = pr_i*pi_j - pi_i*pr_j
//
// Stage 1: 20 blocks, block b=(k*10+slice) sums ij in [slice*10, slice*10+10)
//          -> partial P[b*100 + a] in d_ws (fully written, no memset needed).
// Stage 2: gemv folds the 10 partials per (k,a) into LDS sM, then tiled GEMV.
//          128 rows/block, 640 threads: staging is exactly 5 float4/thread
//          (no divergent tail), P-fold redundancy halved vs 64-row tiles.

#define T_ROWS 262144
#define NF 100
#define ROWS 128          // rows per gemv block
#define GTHREADS 640      // 10 waves; staging = ROWS*25/GTHREADS = 5 float4 each

// clang ext vector types: layout-identical to float4/float2 but accepted by
// __builtin_nontemporal_{load,store} (HIP_vector_type is a class -> rejected).
typedef float fvec4 __attribute__((ext_vector_type(4)));
typedef float fvec2 __attribute__((ext_vector_type(2)));

__global__ __launch_bounds__(256) void compute_M_partial(
    const float* __restrict__ A_re, const float* __restrict__ A_im,
    const float* __restrict__ psi_re, const float* __restrict__ psi_im,
    float* __restrict__ P)
{
    __shared__ float u[100], v[100];
    __shared__ float sp[256];
    int t = threadIdx.x;
    int b = blockIdx.x;          // 0..19
    int k = b / 10;              // class
    int slice = b % 10;          // ij decade

    if (t < 100) {
        int i = t / 10, j = t % 10;
        float pri = psi_re[i], pii = psi_im[i];
        float prj = psi_re[j], pij = psi_im[j];
        u[t] = pri * prj + pii * pij;   // Re(conj(psi_i) * psi_j)
        v[t] = pri * pij - pii * prj;   // Im(conj(psi_i) * psi_j)
    }
    __syncthreads();

    float s = 0.f;
    if (t < 200) {
        int ij_off = t / 100;    // 0 or 1
        int a = t % 100;
        const float* Ar = A_re + k * 10000;
        const float* Ai = A_im + k * 10000;
#pragma unroll
        for (int m = 0; m < 5; ++m) {
            int ij = slice * 10 + ij_off + 2 * m;
            // consecutive t -> consecutive a -> coalesced
            s += u[ij] * Ar[ij * 100 + a] - v[ij] * Ai[ij * 100 + a];
        }
    }
    sp[t] = s;
    __syncthreads();
    if (t < 100) {
        P[b * 100 + t] = sp[t] + sp[t + 100];
    }
}

// One block = 128 rows. Stage tile into LDS (coalesced float4, nontemporal),
// 4 threads per row, 25 cols each, shfl_xor reduce, float2 store.
__global__ __launch_bounds__(GTHREADS) void gemv_out(
    const float* __restrict__ x, const float* __restrict__ P,
    float* __restrict__ out)
{
    __shared__ float sx[ROWS * NF];   // 51200 B
    __shared__ float sM[2 * NF];      // 800 B  -> 52000 B total, 3 blocks/CU
    int tid = threadIdx.x;

    // 128 rows * 100 floats = 12800 floats = 3200 float4 = 640 * 5
    const fvec4* xg = (const fvec4*)(x + (long)blockIdx.x * (ROWS * NF));
    fvec4* sx4 = (fvec4*)sx;
#pragma unroll
    for (int it = 0; it < 5; ++it) {
        fvec4 val = __builtin_nontemporal_load(&xg[tid + it * GTHREADS]);
        sx4[tid + it * GTHREADS] = val;
    }

    // Fold the 10 ij-decade partials: sM[k*100+a] = sum_s P[k*1000 + s*100 + a]
    if (tid < 200) {
        int k = tid / 100, a = tid % 100;
        float m = 0.f;
#pragma unroll
        for (int s = 0; s < 10; ++s)
            m += P[k * 1000 + s * 100 + a];
        sM[tid] = m;
    }
    __syncthreads();

    if (tid < 512) {
        int r = tid >> 2;        // row within tile, 0..127
        int c = tid & 3;         // column quarter, 0..3
        const float* xr = sx + r * NF + c * 25;   // LDS addr = 25*tid + j -> 2-way bank alias (free)
        const float* m0 = sM + c * 25;
        const float* m1 = sM + NF + c * 25;
        float s0 = 0.f, s1 = 0.f;
#pragma unroll
        for (int j = 0; j < 25; ++j) {
            float xv = xr[j];
            s0 += xv * m0[j];
            s1 += xv * m1[j];
        }
        // reduce the 4 column-quarters (lanes r*4+c are contiguous in the wave)
        s0 += __shfl_xor(s0, 1); s1 += __shfl_xor(s1, 1);
        s0 += __shfl_xor(s0, 2); s1 += __shfl_xor(s1, 2);

        if (c == 0) {
            long row = (long)blockIdx.x * ROWS + r;
            fvec2 o; o.x = s0; o.y = s1;
            __builtin_nontemporal_store(o, &((fvec2*)out)[row]);
        }
    }
}

extern "C" void kernel_launch(void* const* d_in, const int* in_sizes, int n_in,
                              void* d_out, int out_size, void* d_ws, size_t ws_size,
                              hipStream_t stream) {
    const float* x      = (const float*)d_in[0];
    const float* A_re   = (const float*)d_in[1];
    const float* A_im   = (const float*)d_in[2];
    const float* psi_re = (const float*)d_in[3];
    const float* psi_im = (const float*)d_in[4];
    float* out = (float*)d_out;
    float* P   = (float*)d_ws;   // 20*100 floats of partials

    compute_M_partial<<<20, 256, 0, stream>>>(A_re, A_im, psi_re, psi_im, P);
    gemv_out<<<T_ROWS / ROWS, GTHREADS, 0, stream>>>(x, P, out);
}